// Round 6
// baseline (337.999 us; speedup 1.0000x reference)
//
#include <hip/hip_runtime.h>
#include <hip/hip_bf16.h>

// GCN encoder: two graph-conv layers on N=50000 nodes, E=800000 edges.
// R6: (1) rank-in-deg removes place's atomics; (2) slice-partitioned csr +
// blockIdx%8 XCD swizzle so each csr line is dirtied by one XCD only (R5
// showed 52.6MB HBM write for a 3.2MB buffer = ~8x cross-XCD line eviction);
// (3) gemm2 (t = h@W2rel^T) fused into gemm1's epilogue via LDS round-trip.
// Layer1: agg1 = segsum(x[src]!=self, dst);  h = relu(agg1@W1r^T + x@W1s^T + b1)
// Layer2: t = h@W2r^T; agg2 = segsum(t[src], dst); out = agg2 + b2 + h@W2s^T

#define N_NODES 50000
#define F_IN    96
#define HIDDEN  128
#define OUT_F   64

// ---------------- CSR build ------------------------------------------------
// pass 1: degree count + per-edge rank within its dst segment
__global__ __launch_bounds__(256) void deg_rank_kernel(
    const int* __restrict__ ei, int* __restrict__ deg,
    int* __restrict__ rank, int E)
{
    int e = blockIdx.x * 256 + threadIdx.x;
    if (e >= E) return;
    int s = ei[e], d = ei[E + e];
    if (s != d && (unsigned)d < (unsigned)N_NODES)
        rank[e] = atomicAdd(&deg[d], 1);     // remove_self_loops
}

// per-slice, order-free segment allocation: off[n] = within-slice offset
__global__ __launch_bounds__(256) void alloc_kernel(
    const int* __restrict__ deg, int* __restrict__ off,
    int* __restrict__ counter, int N, int slice_size)
{
    int i = blockIdx.x * 256 + threadIdx.x;
    int lane = threadIdx.x & 63;
    int v = (i < N) ? deg[i] : 0;
    int s = v;                                // inclusive scan over the wave
    #pragma unroll
    for (int d = 1; d < 64; d <<= 1) {
        int t = __shfl_up(s, d, 64);
        if (lane >= d) s += t;
    }
    int total = __shfl(s, 63, 64);
    int sl = (blockIdx.x * 256) / slice_size; // block fully inside one slice
    int base = 0;
    if (lane == 63) base = atomicAdd(&counter[sl], total);
    base = __shfl(base, 63, 64);
    if (i < N) off[i] = base + s - v;         // exclusive prefix within slice
}

// scan the 8 slice totals -> slice base addresses in csr
__global__ void scan8_kernel(const int* __restrict__ counter,
                             int* __restrict__ sbase)
{
    if (threadIdx.x == 0) {
        int run = 0;
        for (int s = 0; s < 8; ++s) { sbase[s] = run; run += counter[s]; }
    }
}

// pass 2: placement, no atomics. blockIdx%8 -> slice (~XCD id on 8-XCD part):
// each csr line is written by blocks of a single XCD -> single eviction.
__global__ __launch_bounds__(256) void place_kernel(
    const int* __restrict__ ei, const int* __restrict__ off,
    const int* __restrict__ rank, const int* __restrict__ sbase,
    int* __restrict__ csr, int E, int slice_size)
{
    int sl = blockIdx.x & 7;
    int chunk = blockIdx.x >> 3;
    int base = chunk * 2048 + threadIdx.x;
    int sb = sbase[sl];
    #pragma unroll
    for (int i = 0; i < 8; ++i) {
        int e = base + i * 256;
        if (e >= E) break;                    // monotone in i per thread
        int s = ei[e], d = ei[E + e];
        if (s == d) continue;
        if ((unsigned)d >= (unsigned)N_NODES) continue;
        if (d / slice_size != sl) continue;   // not my slice
        int p = sb + off[d] + rank[e];
        if ((unsigned)p < (unsigned)E)        // guard: invariant p < E
            csr[p] = s;
    }
}

// ---------------- gather aggregation: agg[n] = sum_{e: dst=n} feat[src_e] ----
template<int F>
__global__ __launch_bounds__(256) void gather_agg(
    const float* __restrict__ feat, const int* __restrict__ off,
    const int* __restrict__ deg, const int* __restrict__ sbase,
    const int* __restrict__ csr, float* __restrict__ agg,
    int N, int E, int slice_size)
{
    constexpr int C = F / 4;
    int gid = blockIdx.x * 256 + threadIdx.x;
    int node = gid / C;
    int c = gid % C;
    if (node >= N) return;
    int j = sbase[node / slice_size] + off[node];
    int end = j + deg[node];
    if (j < 0) j = 0;                         // guards (no-ops when sane)
    if (end > E) end = E;
    float4 acc = make_float4(0.f, 0.f, 0.f, 0.f);
    for (; j + 1 < end; j += 2) {
        int s0 = csr[j], s1 = csr[j + 1];
        float4 v0 = *(const float4*)&feat[(size_t)s0 * F + c * 4];
        float4 v1 = *(const float4*)&feat[(size_t)s1 * F + c * 4];
        acc.x += v0.x + v1.x; acc.y += v0.y + v1.y;
        acc.z += v0.z + v1.z; acc.w += v0.w + v1.w;
    }
    if (j < end) {
        int s0 = csr[j];
        float4 v0 = *(const float4*)&feat[(size_t)s0 * F + c * 4];
        acc.x += v0.x; acc.y += v0.y; acc.z += v0.z; acc.w += v0.w;
    }
    *(float4*)&agg[(size_t)node * F + c * 4] = acc;
}

// ---------------- fused layer-1 GEMM + t-projection -------------------------
// h = relu(agg1@W1rel^T + x@W1root^T + b1)   [32 nodes x 128 per block]
// t = h@W2rel^T                              [32 nodes x 64, via LDS h tile]
__global__ __launch_bounds__(256) void gemm1_fused(
    const float* __restrict__ agg1, const float* __restrict__ x,
    const float* __restrict__ W1_rel, const float* __restrict__ W1_root,
    const float* __restrict__ b1, const float* __restrict__ W2_rel,
    float* __restrict__ h, float* __restrict__ t, int N)
{
    union SMem {
        struct { float As[8][36]; float Ws[8][128]; } p1;   // 5.2 KB
        struct { float hs[32][132]; float W2s[64][132]; } p2; // 50.7 KB
    };
    __shared__ SMem sm;
    const int tid = threadIdx.x;
    const int nblock = blockIdx.x * 32;
    const int n0 = (tid % 8) * 4;
    const int j0 = (tid / 8) * 4;
    float acc[4][4] = {};

    for (int c = 0; c < 24; ++c) {            // 12 chunks agg1@W1rel, 12 x@W1root
        const float* __restrict__ A = (c < 12) ? agg1 : x;
        const float* __restrict__ W = (c < 12) ? W1_rel : W1_root;
        const int kbase = (c % 12) * 8;
        {
            int n = tid / 8, k = tid % 8;
            int node = nblock + n;
            sm.p1.As[k][n] = (node < N) ? A[(size_t)node * 96 + kbase + k] : 0.f;
        }
        {
            int j = tid / 2, koff = (tid % 2) * 4;
            float4 w = *(const float4*)&W[(size_t)j * 96 + kbase + koff];
            sm.p1.Ws[koff + 0][j] = w.x; sm.p1.Ws[koff + 1][j] = w.y;
            sm.p1.Ws[koff + 2][j] = w.z; sm.p1.Ws[koff + 3][j] = w.w;
        }
        __syncthreads();
        #pragma unroll
        for (int k = 0; k < 8; ++k) {
            float4 av = *(const float4*)&sm.p1.As[k][n0];
            float4 wv = *(const float4*)&sm.p1.Ws[k][j0];
            float a[4] = {av.x, av.y, av.z, av.w};
            float w[4] = {wv.x, wv.y, wv.z, wv.w};
            #pragma unroll
            for (int i = 0; i < 4; ++i)
                #pragma unroll
                for (int jj = 0; jj < 4; ++jj)
                    acc[i][jj] += a[i] * w[jj];
        }
        __syncthreads();
    }

    // epilogue: h tile -> global + LDS (OOB rows hold junk, never consumed)
    float bj[4] = {b1[j0], b1[j0 + 1], b1[j0 + 2], b1[j0 + 3]};
    #pragma unroll
    for (int i = 0; i < 4; ++i) {
        int node = nblock + n0 + i;
        float4 o;
        o.x = fmaxf(acc[i][0] + bj[0], 0.f);
        o.y = fmaxf(acc[i][1] + bj[1], 0.f);
        o.z = fmaxf(acc[i][2] + bj[2], 0.f);
        o.w = fmaxf(acc[i][3] + bj[3], 0.f);
        *(float4*)&sm.p2.hs[n0 + i][j0] = o;
        if (node < N) *(float4*)&h[(size_t)node * 128 + j0] = o;
    }
    // stage W2rel [64][128] row-major (coalesced float4 loads)
    for (int idx = tid; idx < 64 * 32; idx += 256) {
        int o = idx >> 5, kq = (idx & 31) << 2;
        float4 w = *(const float4*)&W2_rel[(size_t)o * 128 + kq];
        *(float4*)&sm.p2.W2s[o][kq] = w;
    }
    __syncthreads();

    // t phase: 2 rows x 4 cols per thread, k-vectorized
    const int n0t = (tid & 15) * 2;
    const int o0 = (tid >> 4) * 4;
    float acc2[2][4] = {};
    #pragma unroll 8
    for (int k4 = 0; k4 < 128; k4 += 4) {
        float4 h0 = *(const float4*)&sm.p2.hs[n0t][k4];
        float4 h1 = *(const float4*)&sm.p2.hs[n0t + 1][k4];
        #pragma unroll
        for (int j = 0; j < 4; ++j) {
            float4 w = *(const float4*)&sm.p2.W2s[o0 + j][k4];
            acc2[0][j] += h0.x * w.x + h0.y * w.y + h0.z * w.z + h0.w * w.w;
            acc2[1][j] += h1.x * w.x + h1.y * w.y + h1.z * w.z + h1.w * w.w;
        }
    }
    #pragma unroll
    for (int r = 0; r < 2; ++r) {
        int node = nblock + n0t + r;
        if (node < N)
            *(float4*)&t[(size_t)node * 64 + o0] =
                make_float4(acc2[r][0], acc2[r][1], acc2[r][2], acc2[r][3]);
    }
}

// ---------------- tiled fp32 GEMM (final layer): C = A@W^T + b + addend ------
template<int J, int K, int TILE_N>
__global__ __launch_bounds__(256) void gemm_final(
    const float* __restrict__ A, const float* __restrict__ W,
    const float* __restrict__ bias, const float* __restrict__ addend,
    float* __restrict__ C, int N)
{
    constexpr int KC = 8;
    __shared__ float As[KC][TILE_N + 4];
    __shared__ float Ws[KC][J];
    const int tid = threadIdx.x;
    const int nblock = blockIdx.x * TILE_N;
    constexpr int NGRP = TILE_N / 4;
    const int n0 = (tid % NGRP) * 4;
    const int j0 = (tid / NGRP) * 4;
    float acc[4][4] = {};

    for (int c = 0; c < K / KC; ++c) {
        const int kbase = c * KC;
        {   // TILE_N == 64 staging
            int n = tid / 4, k = (tid % 4) * 2;
            int node = nblock + n;
            float2 v = make_float2(0.f, 0.f);
            if (node < N) v = *(const float2*)&A[(size_t)node * K + kbase + k];
            As[k][n] = v.x;
            As[k + 1][n] = v.y;
        }
        {   // J == 64 staging
            int j = tid / 4, koff = (tid % 4) * 2;
            float2 w = *(const float2*)&W[(size_t)j * K + kbase + koff];
            Ws[koff + 0][j] = w.x;
            Ws[koff + 1][j] = w.y;
        }
        __syncthreads();
        #pragma unroll
        for (int k = 0; k < KC; ++k) {
            float4 av = *(const float4*)&As[k][n0];
            float4 wv = *(const float4*)&Ws[k][j0];
            float a[4] = {av.x, av.y, av.z, av.w};
            float w[4] = {wv.x, wv.y, wv.z, wv.w};
            #pragma unroll
            for (int i = 0; i < 4; ++i)
                #pragma unroll
                for (int jj = 0; jj < 4; ++jj)
                    acc[i][jj] += a[i] * w[jj];
        }
        __syncthreads();
    }

    float bj[4] = {bias[j0], bias[j0 + 1], bias[j0 + 2], bias[j0 + 3]};
    #pragma unroll
    for (int i = 0; i < 4; ++i) {
        int node = nblock + n0 + i;
        if (node >= N) continue;
        float4 ad = *(const float4*)&addend[(size_t)node * J + j0];
        float4 o;
        o.x = acc[i][0] + bj[0] + ad.x;
        o.y = acc[i][1] + bj[1] + ad.y;
        o.z = acc[i][2] + bj[2] + ad.z;
        o.w = acc[i][3] + bj[3] + ad.w;
        *(float4*)&C[(size_t)node * J + j0] = o;
    }
}

extern "C" void kernel_launch(void* const* d_in, const int* in_sizes, int n_in,
                              void* d_out, int out_size, void* d_ws, size_t ws_size,
                              hipStream_t stream) {
    const float* x       = (const float*)d_in[0];
    const int*   ei      = (const int*)d_in[1];
    const float* W1_rel  = (const float*)d_in[2];
    const float* b1      = (const float*)d_in[3];
    const float* W1_root = (const float*)d_in[4];
    const float* W2_rel  = (const float*)d_in[5];
    const float* b2      = (const float*)d_in[6];
    const float* W2_root = (const float*)d_in[7];
    float* out = (float*)d_out;

    const int N = in_sizes[0] / F_IN;       // 50000
    const int E = in_sizes[1] / 2;          // 800000
    const int slice_size = ((N + 2047) / 2048) * 256;  // mult of 256, 8 slices

    // Workspace (peak ~64.4 MB):
    //   [0, 25.6M)        h
    //   [25.6M, 44.8M)    agg1 (19.2M); agg2 aliases first 12.8M (agg1 dead
    //                     after gemm1_fused, agg2 written after)
    //   [44.8M, 57.6M)    t   (live during gemm1_fused while agg1 live!)
    //   [57.6M, ...)      deg/counter8/off/sbase8/rank/csr (~6.8M)
    char* ws = (char*)d_ws;
    const size_t SZ_H = (size_t)N_NODES * HIDDEN * 4;
    const size_t SZ_A = (size_t)N_NODES * F_IN * 4;
    const size_t SZ_T = (size_t)N_NODES * OUT_F * 4;
    float* h    = (float*)(ws);
    float* agg1 = (float*)(ws + SZ_H);
    float* agg2 = (float*)(ws + SZ_H);                 // aliases agg1
    float* t    = (float*)(ws + SZ_H + SZ_A);
    char* ip = ws + SZ_H + SZ_A + SZ_T;
    int* deg     = (int*)(ip);         ip += (size_t)N_NODES * 4;
    int* counter = (int*)(ip);         ip += 8 * 4;    // contiguous w/ deg
    int* off     = (int*)(ip);         ip += (size_t)N_NODES * 4;
    int* sbase   = (int*)(ip);         ip += 8 * 4;
    int* rank    = (int*)(ip);         ip += (size_t)E * 4;
    int* csr     = (int*)(ip);

    // ---- CSR build (shared by both layers) ----
    hipMemsetAsync(deg, 0, ((size_t)N + 8) * 4, stream);   // deg + counter
    deg_rank_kernel<<<(E + 255) / 256, 256, 0, stream>>>(ei, deg, rank, E);
    alloc_kernel<<<(N + 255) / 256, 256, 0, stream>>>(deg, off, counter, N, slice_size);
    scan8_kernel<<<1, 64, 0, stream>>>(counter, sbase);
    {
        int chunks = (E + 2047) / 2048;
        place_kernel<<<chunks * 8, 256, 0, stream>>>(ei, off, rank, sbase, csr, E, slice_size);
    }

    // ---- layer 1 (+ fused t = h@W2rel^T) ----
    {
        int total = N * (F_IN / 4);
        gather_agg<F_IN><<<(total + 255) / 256, 256, 0, stream>>>(
            x, off, deg, sbase, csr, agg1, N, E, slice_size);
    }
    gemm1_fused<<<(N + 31) / 32, 256, 0, stream>>>(
        agg1, x, W1_rel, W1_root, b1, W2_rel, h, t, N);

    // ---- layer 2 ----
    {
        int total = N * (OUT_F / 4);
        gather_agg<OUT_F><<<(total + 255) / 256, 256, 0, stream>>>(
            t, off, deg, sbase, csr, agg2, N, E, slice_size);
    }
    gemm_final<OUT_F, HIDDEN, 64><<<(N + 63) / 64, 256, 0, stream>>>(
        h, W2_root, b2, agg2, out, N);
}

// Round 7
// 298.385 us; speedup vs baseline: 1.1328x; 1.1328x over previous
//
#include <hip/hip_runtime.h>
#include <hip/hip_bf16.h>

// GCN encoder: two graph-conv layers on N=50000 nodes, E=800000 edges.
// R7 = R6's CSR build (rank-in-deg pass kills place atomics; slice-partitioned
// csr + blockIdx%8 swizzle kills cross-XCD line eviction) + R5's UNfused
// small-LDS GEMMs (R6's fusion regressed: 50.7KB LDS union -> 25% occupancy,
// 12.6M bank conflicts from 132-stride epilogue tiles, 111us).
// Layer1: agg1 = segsum(x[src]!=self, dst);  h = relu(agg1@W1r^T + x@W1s^T + b1)
// Layer2: t = h@W2r^T; agg2 = segsum(t[src], dst); out = agg2 + b2 + h@W2s^T

#define N_NODES 50000
#define F_IN    96
#define HIDDEN  128
#define OUT_F   64

// ---------------- CSR build ------------------------------------------------
// pass 1: degree count + per-edge rank within its dst segment
__global__ __launch_bounds__(256) void deg_rank_kernel(
    const int* __restrict__ ei, int* __restrict__ deg,
    int* __restrict__ rank, int E)
{
    int e = blockIdx.x * 256 + threadIdx.x;
    if (e >= E) return;
    int s = ei[e], d = ei[E + e];
    if (s != d && (unsigned)d < (unsigned)N_NODES)
        rank[e] = atomicAdd(&deg[d], 1);     // remove_self_loops
}

// per-slice, order-free segment allocation: off[n] = within-slice offset
__global__ __launch_bounds__(256) void alloc_kernel(
    const int* __restrict__ deg, int* __restrict__ off,
    int* __restrict__ counter, int N, int slice_size)
{
    int i = blockIdx.x * 256 + threadIdx.x;
    int lane = threadIdx.x & 63;
    int v = (i < N) ? deg[i] : 0;
    int s = v;                                // inclusive scan over the wave
    #pragma unroll
    for (int d = 1; d < 64; d <<= 1) {
        int t = __shfl_up(s, d, 64);
        if (lane >= d) s += t;
    }
    int total = __shfl(s, 63, 64);
    int sl = (blockIdx.x * 256) / slice_size; // block fully inside one slice
    int base = 0;
    if (lane == 63) base = atomicAdd(&counter[sl], total);
    base = __shfl(base, 63, 64);
    if (i < N) off[i] = base + s - v;         // exclusive prefix within slice
}

// scan the 8 slice totals -> slice base addresses in csr
__global__ void scan8_kernel(const int* __restrict__ counter,
                             int* __restrict__ sbase)
{
    if (threadIdx.x == 0) {
        int run = 0;
        for (int s = 0; s < 8; ++s) { sbase[s] = run; run += counter[s]; }
    }
}

// pass 2: placement, no atomics. blockIdx%8 -> slice (~XCD id on 8-XCD part):
// each csr line is written by blocks of a single XCD -> single eviction.
__global__ __launch_bounds__(256) void place_kernel(
    const int* __restrict__ ei, const int* __restrict__ off,
    const int* __restrict__ rank, const int* __restrict__ sbase,
    int* __restrict__ csr, int E, int slice_size)
{
    int sl = blockIdx.x & 7;
    int chunk = blockIdx.x >> 3;
    int base = chunk * 2048 + threadIdx.x;
    int sb = sbase[sl];
    #pragma unroll
    for (int i = 0; i < 8; ++i) {
        int e = base + i * 256;
        if (e >= E) break;                    // monotone in i per thread
        int s = ei[e], d = ei[E + e];
        if (s == d) continue;
        if ((unsigned)d >= (unsigned)N_NODES) continue;
        if (d / slice_size != sl) continue;   // not my slice
        int p = sb + off[d] + rank[e];
        if ((unsigned)p < (unsigned)E)        // guard: invariant p < E
            csr[p] = s;
    }
}

// ---------------- gather aggregation: agg[n] = sum_{e: dst=n} feat[src_e] ----
template<int F>
__global__ __launch_bounds__(256) void gather_agg(
    const float* __restrict__ feat, const int* __restrict__ off,
    const int* __restrict__ deg, const int* __restrict__ sbase,
    const int* __restrict__ csr, float* __restrict__ agg,
    int N, int E, int slice_size)
{
    constexpr int C = F / 4;
    int gid = blockIdx.x * 256 + threadIdx.x;
    int node = gid / C;
    int c = gid % C;
    if (node >= N) return;
    int j = sbase[node / slice_size] + off[node];
    int end = j + deg[node];
    if (j < 0) j = 0;                         // guards (no-ops when sane)
    if (end > E) end = E;
    float4 acc = make_float4(0.f, 0.f, 0.f, 0.f);
    for (; j + 1 < end; j += 2) {
        int s0 = csr[j], s1 = csr[j + 1];
        float4 v0 = *(const float4*)&feat[(size_t)s0 * F + c * 4];
        float4 v1 = *(const float4*)&feat[(size_t)s1 * F + c * 4];
        acc.x += v0.x + v1.x; acc.y += v0.y + v1.y;
        acc.z += v0.z + v1.z; acc.w += v0.w + v1.w;
    }
    if (j < end) {
        int s0 = csr[j];
        float4 v0 = *(const float4*)&feat[(size_t)s0 * F + c * 4];
        acc.x += v0.x; acc.y += v0.y; acc.z += v0.z; acc.w += v0.w;
    }
    *(float4*)&agg[(size_t)node * F + c * 4] = acc;
}

// ---------------- tiled fp32 GEMM:  C = act(A1@W1^T [+ A2@W2^T] + b [+ add]) -
template<int J, int K, int TILE_N, bool RELU, bool TWO, bool HAS_BIAS, bool HAS_ADDEND>
__global__ __launch_bounds__(256) void gemm_kernel(
    const float* __restrict__ A1, const float* __restrict__ A2,
    const float* __restrict__ W1, const float* __restrict__ W2,
    const float* __restrict__ bias, const float* __restrict__ addend,
    float* __restrict__ C, int N)
{
    constexpr int KC = 8;
    constexpr int ASTR = TILE_N + 4;
    __shared__ float As[KC][ASTR];
    __shared__ float Ws[KC][J];

    const int tid = threadIdx.x;
    const int nblock = blockIdx.x * TILE_N;
    constexpr int NGRP = TILE_N / 4;
    const int n0 = (tid % NGRP) * 4;
    const int j0 = (tid / NGRP) * 4;

    float acc[4][4] = {};

    constexpr int NCH = K / KC;
    constexpr int TOTCH = TWO ? 2 * NCH : NCH;

    for (int c = 0; c < TOTCH; ++c) {
        const bool second = TWO && (c >= NCH);
        const float* __restrict__ A = second ? A2 : A1;
        const float* __restrict__ W = second ? W2 : W1;
        const int kbase = (c % NCH) * KC;

        if (TILE_N == 32) {
            int n = tid / 8, k = tid % 8;
            int node = nblock + n;
            As[k][n] = (node < N) ? A[(size_t)node * K + kbase + k] : 0.f;
        } else {
            int n = tid / 4, k = (tid % 4) * 2;
            int node = nblock + n;
            float2 v = make_float2(0.f, 0.f);
            if (node < N) v = *(const float2*)&A[(size_t)node * K + kbase + k];
            As[k][n] = v.x;
            As[k + 1][n] = v.y;
        }
        if (J == 128) {
            int j = tid / 2, koff = (tid % 2) * 4;
            float4 w = *(const float4*)&W[(size_t)j * K + kbase + koff];
            Ws[koff + 0][j] = w.x; Ws[koff + 1][j] = w.y;
            Ws[koff + 2][j] = w.z; Ws[koff + 3][j] = w.w;
        } else {
            int j = tid / 4, koff = (tid % 4) * 2;
            float2 w = *(const float2*)&W[(size_t)j * K + kbase + koff];
            Ws[koff + 0][j] = w.x;
            Ws[koff + 1][j] = w.y;
        }
        __syncthreads();

        #pragma unroll
        for (int k = 0; k < KC; ++k) {
            float4 av = *(const float4*)&As[k][n0];
            float4 wv = *(const float4*)&Ws[k][j0];
            float a[4] = {av.x, av.y, av.z, av.w};
            float w[4] = {wv.x, wv.y, wv.z, wv.w};
            #pragma unroll
            for (int i = 0; i < 4; ++i)
                #pragma unroll
                for (int jj = 0; jj < 4; ++jj)
                    acc[i][jj] += a[i] * w[jj];
        }
        __syncthreads();
    }

    float bj[4] = {0.f, 0.f, 0.f, 0.f};
    if (HAS_BIAS) {
        bj[0] = bias[j0 + 0]; bj[1] = bias[j0 + 1];
        bj[2] = bias[j0 + 2]; bj[3] = bias[j0 + 3];
    }
    #pragma unroll
    for (int i = 0; i < 4; ++i) {
        int node = nblock + n0 + i;
        if (node >= N) continue;
        float4 o;
        o.x = acc[i][0] + bj[0];
        o.y = acc[i][1] + bj[1];
        o.z = acc[i][2] + bj[2];
        o.w = acc[i][3] + bj[3];
        if (HAS_ADDEND) {
            float4 ad = *(const float4*)&addend[(size_t)node * J + j0];
            o.x += ad.x; o.y += ad.y; o.z += ad.z; o.w += ad.w;
        }
        if (RELU) {
            o.x = fmaxf(o.x, 0.f); o.y = fmaxf(o.y, 0.f);
            o.z = fmaxf(o.z, 0.f); o.w = fmaxf(o.w, 0.f);
        }
        *(float4*)&C[(size_t)node * J + j0] = o;
    }
}

extern "C" void kernel_launch(void* const* d_in, const int* in_sizes, int n_in,
                              void* d_out, int out_size, void* d_ws, size_t ws_size,
                              hipStream_t stream) {
    const float* x       = (const float*)d_in[0];
    const int*   ei      = (const int*)d_in[1];
    const float* W1_rel  = (const float*)d_in[2];
    const float* b1      = (const float*)d_in[3];
    const float* W1_root = (const float*)d_in[4];
    const float* W2_rel  = (const float*)d_in[5];
    const float* b2      = (const float*)d_in[6];
    const float* W2_root = (const float*)d_in[7];
    float* out = (float*)d_out;

    const int N = in_sizes[0] / F_IN;       // 50000
    const int E = in_sizes[1] / 2;          // 800000
    const int slice_size = ((N + 2047) / 2048) * 256;  // mult of 256, 8 slices

    // Workspace (peak ~58 MB):
    //   [0, 25.6M)      h                  (live: gemm1 -> end)
    //   [25.6M, 44.8M)  agg1 (19.2M)       (live: gather1 -> gemm1)
    //   [25.6M, 38.4M)  t    (12.8M)       (reuses agg1; live gemm2 -> gather2)
    //   [38.4M, 51.2M)  agg2 (12.8M)       (live: gather2 -> gemm3)
    //   [51.2M, ...)    deg/counter8/off/sbase8/rank/csr (~6.8M)
    char* ws = (char*)d_ws;
    const size_t SZ_H = (size_t)N_NODES * HIDDEN * 4;
    const size_t SZ_T = (size_t)N_NODES * OUT_F * 4;
    float* h    = (float*)(ws);
    float* agg1 = (float*)(ws + SZ_H);
    float* t    = (float*)(ws + SZ_H);                 // reuses agg1 region
    float* agg2 = (float*)(ws + SZ_H + SZ_T);
    char* ip = ws + SZ_H + SZ_T + SZ_T;
    int* deg     = (int*)(ip);         ip += (size_t)N_NODES * 4;
    int* counter = (int*)(ip);         ip += 8 * 4;    // contiguous w/ deg
    int* off     = (int*)(ip);         ip += (size_t)N_NODES * 4;
    int* sbase   = (int*)(ip);         ip += 8 * 4;
    int* rank    = (int*)(ip);         ip += (size_t)800000 * 4;
    int* csr     = (int*)(ip);

    // ---- CSR build (shared by both layers) ----
    hipMemsetAsync(deg, 0, ((size_t)N + 8) * 4, stream);   // deg + counter
    deg_rank_kernel<<<(E + 255) / 256, 256, 0, stream>>>(ei, deg, rank, E);
    alloc_kernel<<<(N + 255) / 256, 256, 0, stream>>>(deg, off, counter, N, slice_size);
    scan8_kernel<<<1, 64, 0, stream>>>(counter, sbase);
    {
        int chunks = (E + 2047) / 2048;
        place_kernel<<<chunks * 8, 256, 0, stream>>>(ei, off, rank, sbase, csr, E, slice_size);
    }

    // ---- layer 1 ----
    {
        int total = N * (F_IN / 4);
        gather_agg<F_IN><<<(total + 255) / 256, 256, 0, stream>>>(
            x, off, deg, sbase, csr, agg1, N, E, slice_size);
    }
    gemm_kernel<HIDDEN, F_IN, 32, true, true, true, false>
        <<<(N + 31) / 32, 256, 0, stream>>>(agg1, x, W1_rel, W1_root, b1, nullptr, h, N);

    // ---- layer 2 (projection pushed before the scatter) ----
    gemm_kernel<OUT_F, HIDDEN, 64, false, false, false, false>
        <<<(N + 63) / 64, 256, 0, stream>>>(h, nullptr, W2_rel, nullptr, nullptr, nullptr, t, N);
    {
        int total = N * (OUT_F / 4);
        gather_agg<OUT_F><<<(total + 255) / 256, 256, 0, stream>>>(
            t, off, deg, sbase, csr, agg2, N, E, slice_size);
    }
    gemm_kernel<OUT_F, HIDDEN, 64, false, false, true, true>
        <<<(N + 63) / 64, 256, 0, stream>>>(h, nullptr, W2_root, nullptr, b2, agg2, out, N);
}

// Round 8
// 254.447 us; speedup vs baseline: 1.3284x; 1.1727x over previous
//
#include <hip/hip_runtime.h>

// GCN encoder, N=50000, E=800000.
// R8: GEMMs moved to bf16 MFMA (16x16x32), LDS-free: A and W fragments are
// 8 contiguous bf16 (16B) loads straight from L2 in the HW fragment layout.
//   A[m=lane&15][k=quad*8+j], B[k=quad*8+j][n=lane&15], C: col=lane&15,
//   row=quad*4+reg  (layouts HW-verified per guide m89/m91/m120).
// Features cast to bf16 once; gathers move bf16 (half traffic); h,t bf16.
// CSR build unchanged from R7 (rank-in-deg, sliced atomic-free place).

#define N_NODES 50000
#define F_IN    96
#define HIDDEN  128
#define OUT_F   64

typedef __attribute__((ext_vector_type(8))) short short8;
typedef __attribute__((ext_vector_type(4))) float floatx4;

__device__ inline unsigned short f2bf(float f) {          // RNE f32->bf16
    union { float f; unsigned u; } v; v.f = f;
    unsigned r = v.u + 0x7FFF + ((v.u >> 16) & 1);
    return (unsigned short)(r >> 16);
}
__device__ inline float bf2f(unsigned short b) {
    union { unsigned u; float f; } v; v.u = ((unsigned)b) << 16;
    return v.f;
}

// ---------------- dtype conversion ------------------------------------------
__global__ __launch_bounds__(256) void convert_x_kernel(
    const float* __restrict__ x, unsigned short* __restrict__ xb, int total8)
{
    int i = blockIdx.x * 256 + threadIdx.x;
    if (i >= total8) return;
    const float4* p = (const float4*)(x + (size_t)i * 8);
    float4 v0 = p[0], v1 = p[1];
    short8 o;
    o[0] = (short)f2bf(v0.x); o[1] = (short)f2bf(v0.y);
    o[2] = (short)f2bf(v0.z); o[3] = (short)f2bf(v0.w);
    o[4] = (short)f2bf(v1.x); o[5] = (short)f2bf(v1.y);
    o[6] = (short)f2bf(v1.z); o[7] = (short)f2bf(v1.w);
    *(short8*)(xb + (size_t)i * 8) = o;
}

// W1b[j][k] = k<96 ? W1_rel[j][k] : W1_root[j][k-96]  (128x192)
// W2rb = bf16(W2_rel) (64x128), W2sb = bf16(W2_root) (64x128)
__global__ __launch_bounds__(256) void convert_w_kernel(
    const float* __restrict__ W1_rel, const float* __restrict__ W1_root,
    const float* __restrict__ W2_rel, const float* __restrict__ W2_root,
    unsigned short* __restrict__ W1b, unsigned short* __restrict__ W2rb,
    unsigned short* __restrict__ W2sb)
{
    int i = blockIdx.x * 256 + threadIdx.x;
    if (i < 128 * 192) {
        int j = i / 192, k = i % 192;
        float v = (k < 96) ? W1_rel[j * 96 + k] : W1_root[j * 96 + k - 96];
        W1b[i] = f2bf(v);
    }
    int i2 = i - 128 * 192;
    if (i2 >= 0 && i2 < 64 * 128) W2rb[i2] = f2bf(W2_rel[i2]);
    int i3 = i2 - 64 * 128;
    if (i3 >= 0 && i3 < 64 * 128) W2sb[i3] = f2bf(W2_root[i3]);
}

// ---------------- CSR build (R7, verified) ----------------------------------
__global__ __launch_bounds__(256) void deg_rank_kernel(
    const int* __restrict__ ei, int* __restrict__ deg,
    int* __restrict__ rank, int E)
{
    int e = blockIdx.x * 256 + threadIdx.x;
    if (e >= E) return;
    int s = ei[e], d = ei[E + e];
    if (s != d && (unsigned)d < (unsigned)N_NODES)
        rank[e] = atomicAdd(&deg[d], 1);
}

__global__ __launch_bounds__(256) void alloc_kernel(
    const int* __restrict__ deg, int* __restrict__ off,
    int* __restrict__ counter, int N, int slice_size)
{
    int i = blockIdx.x * 256 + threadIdx.x;
    int lane = threadIdx.x & 63;
    int v = (i < N) ? deg[i] : 0;
    int s = v;
    #pragma unroll
    for (int d = 1; d < 64; d <<= 1) {
        int t = __shfl_up(s, d, 64);
        if (lane >= d) s += t;
    }
    int total = __shfl(s, 63, 64);
    int sl = (blockIdx.x * 256) / slice_size;
    int base = 0;
    if (lane == 63) base = atomicAdd(&counter[sl], total);
    base = __shfl(base, 63, 64);
    if (i < N) off[i] = base + s - v;
}

__global__ void scan8_kernel(const int* __restrict__ counter,
                             int* __restrict__ sbase)
{
    if (threadIdx.x == 0) {
        int run = 0;
        for (int s = 0; s < 8; ++s) { sbase[s] = run; run += counter[s]; }
    }
}

__global__ __launch_bounds__(256) void place_kernel(
    const int* __restrict__ ei, const int* __restrict__ off,
    const int* __restrict__ rank, const int* __restrict__ sbase,
    int* __restrict__ csr, int E, int slice_size)
{
    int sl = blockIdx.x & 7;
    int chunk = blockIdx.x >> 3;
    int base = chunk * 2048 + threadIdx.x;
    int sb = sbase[sl];
    #pragma unroll
    for (int i = 0; i < 8; ++i) {
        int e = base + i * 256;
        if (e >= E) break;
        int s = ei[e], d = ei[E + e];
        if (s == d) continue;
        if ((unsigned)d >= (unsigned)N_NODES) continue;
        if (d / slice_size != sl) continue;
        int p = sb + off[d] + rank[e];
        if ((unsigned)p < (unsigned)E)
            csr[p] = s;
    }
}

// ---------------- gather (bf16 feats): agg[n] = sum feat[src] ----------------
template<int F, bool OUT_BF>
__global__ __launch_bounds__(256) void gather_agg_bf(
    const unsigned short* __restrict__ feat, const int* __restrict__ off,
    const int* __restrict__ deg, const int* __restrict__ sbase,
    const int* __restrict__ csr, void* __restrict__ agg,
    int N, int E, int slice_size)
{
    constexpr int C = F / 8;
    int gid = blockIdx.x * 256 + threadIdx.x;
    int node = gid / C;
    int c = gid % C;
    if (node >= N) return;
    int j = sbase[node / slice_size] + off[node];
    int end = j + deg[node];
    if (j < 0) j = 0;
    if (end > E) end = E;
    float acc[8] = {};
    for (; j + 1 < end; j += 2) {
        int s0 = csr[j], s1 = csr[j + 1];
        short8 v0 = *(const short8*)(feat + (size_t)s0 * F + c * 8);
        short8 v1 = *(const short8*)(feat + (size_t)s1 * F + c * 8);
        #pragma unroll
        for (int i = 0; i < 8; ++i)
            acc[i] += bf2f((unsigned short)v0[i]) + bf2f((unsigned short)v1[i]);
    }
    if (j < end) {
        int s0 = csr[j];
        short8 v0 = *(const short8*)(feat + (size_t)s0 * F + c * 8);
        #pragma unroll
        for (int i = 0; i < 8; ++i) acc[i] += bf2f((unsigned short)v0[i]);
    }
    if (OUT_BF) {
        short8 o;
        #pragma unroll
        for (int i = 0; i < 8; ++i) o[i] = (short)f2bf(acc[i]);
        *(short8*)((unsigned short*)agg + (size_t)node * F + c * 8) = o;
    } else {
        float* ap = (float*)agg + (size_t)node * F + c * 8;
        floatx4 lo = {acc[0], acc[1], acc[2], acc[3]};
        floatx4 hi = {acc[4], acc[5], acc[6], acc[7]};
        *(floatx4*)ap = lo;
        *(floatx4*)(ap + 4) = hi;
    }
}

// ---------------- MFMA GEMM: out = act(A@W^T + b [+ add]) --------------------
// A: [N,KT] bf16 row-major (SPLIT: two halves in A1/A2), W: [NO,KT] bf16.
// LDS-free: per-lane 16B fragment loads straight from L2.
template<int KT, int NO, bool SPLIT, bool RELU, bool HAS_BIAS, bool HAS_ADD, bool OUT_BF>
__global__ __launch_bounds__(256) void gemm_mfma(
    const unsigned short* __restrict__ A1, const unsigned short* __restrict__ A2,
    const unsigned short* __restrict__ W, const float* __restrict__ bias,
    const float* __restrict__ add, void* __restrict__ out, int N)
{
    constexpr int NC = KT / 32;
    const int lane = threadIdx.x & 63;
    const int wave = threadIdx.x >> 6;
    const int node_base = blockIdx.x * 64 + wave * 16;
    const int m = lane & 15, quad = lane >> 4;
    int na = node_base + m;
    if (na >= N) na = N - 1;                  // clamp: C rows >=N never stored
    short8 a[NC];
    #pragma unroll
    for (int c = 0; c < NC; ++c) {
        if (SPLIT) {
            constexpr int HK = KT / 2;
            if (c < NC / 2)
                a[c] = *(const short8*)(A1 + (size_t)na * HK + c * 32 + quad * 8);
            else
                a[c] = *(const short8*)(A2 + (size_t)na * HK + (c - NC / 2) * 32 + quad * 8);
        } else {
            a[c] = *(const short8*)(A1 + (size_t)na * KT + c * 32 + quad * 8);
        }
    }
    #pragma unroll
    for (int jt = 0; jt < NO / 16; ++jt) {
        floatx4 acc = {0.f, 0.f, 0.f, 0.f};
        const unsigned short* wb = W + (size_t)(jt * 16 + m) * KT + quad * 8;
        #pragma unroll
        for (int c = 0; c < NC; ++c) {
            short8 b = *(const short8*)(wb + c * 32);
            acc = __builtin_amdgcn_mfma_f32_16x16x32_bf16(a[c], b, acc, 0, 0, 0);
        }
        int col = jt * 16 + m;
        float bv = HAS_BIAS ? bias[col] : 0.f;
        #pragma unroll
        for (int r = 0; r < 4; ++r) {
            int node = node_base + quad * 4 + r;
            if (node < N) {
                float v = acc[r] + bv;
                if (HAS_ADD) v += add[(size_t)node * NO + col];
                if (RELU) v = fmaxf(v, 0.f);
                if (OUT_BF) ((unsigned short*)out)[(size_t)node * NO + col] = f2bf(v);
                else        ((float*)out)[(size_t)node * NO + col] = v;
            }
        }
    }
}

extern "C" void kernel_launch(void* const* d_in, const int* in_sizes, int n_in,
                              void* d_out, int out_size, void* d_ws, size_t ws_size,
                              hipStream_t stream) {
    const float* x       = (const float*)d_in[0];
    const int*   ei      = (const int*)d_in[1];
    const float* W1_rel  = (const float*)d_in[2];
    const float* b1      = (const float*)d_in[3];
    const float* W1_root = (const float*)d_in[4];
    const float* W2_rel  = (const float*)d_in[5];
    const float* b2      = (const float*)d_in[6];
    const float* W2_root = (const float*)d_in[7];
    float* out = (float*)d_out;

    const int N = in_sizes[0] / F_IN;       // 50000
    const int E = in_sizes[1] / 2;          // 800000
    const int slice_size = ((N + 2047) / 2048) * 256;

    // Workspace (~58 MB, no aliasing):
    char* ws = (char*)d_ws;
    size_t p = 0;
    unsigned short* xb    = (unsigned short*)(ws + p); p += (size_t)N_NODES * F_IN * 2;   // 9.6M
    unsigned short* agg1b = (unsigned short*)(ws + p); p += (size_t)N_NODES * F_IN * 2;   // 9.6M
    unsigned short* h     = (unsigned short*)(ws + p); p += (size_t)N_NODES * HIDDEN * 2; // 12.8M
    unsigned short* t     = (unsigned short*)(ws + p); p += (size_t)N_NODES * OUT_F * 2;  // 6.4M
    float* agg2           = (float*)(ws + p);          p += (size_t)N_NODES * OUT_F * 4;  // 12.8M
    unsigned short* W1b   = (unsigned short*)(ws + p); p += (size_t)128 * 192 * 2;
    unsigned short* W2rb  = (unsigned short*)(ws + p); p += (size_t)64 * 128 * 2;
    unsigned short* W2sb  = (unsigned short*)(ws + p); p += (size_t)64 * 128 * 2;
    int* deg     = (int*)(ws + p);  p += (size_t)N_NODES * 4;
    int* counter = (int*)(ws + p);  p += 8 * 4;
    int* off     = (int*)(ws + p);  p += (size_t)N_NODES * 4;
    int* sbase   = (int*)(ws + p);  p += 8 * 4;
    int* rank    = (int*)(ws + p);  p += (size_t)800000 * 4;
    int* csr     = (int*)(ws + p);

    // ---- conversions + CSR build ----
    hipMemsetAsync(deg, 0, ((size_t)N + 8) * 4, stream);   // deg + counter
    {
        int total8 = N * F_IN / 8;          // 600000
        convert_x_kernel<<<(total8 + 255) / 256, 256, 0, stream>>>(x, xb, total8);
    }
    convert_w_kernel<<<160, 256, 0, stream>>>(W1_rel, W1_root, W2_rel, W2_root,
                                              W1b, W2rb, W2sb);
    deg_rank_kernel<<<(E + 255) / 256, 256, 0, stream>>>(ei, deg, rank, E);
    alloc_kernel<<<(N + 255) / 256, 256, 0, stream>>>(deg, off, counter, N, slice_size);
    scan8_kernel<<<1, 64, 0, stream>>>(counter, sbase);
    {
        int chunks = (E + 2047) / 2048;
        place_kernel<<<chunks * 8, 256, 0, stream>>>(ei, off, rank, sbase, csr, E, slice_size);
    }

    const int gemm_blocks = (N + 63) / 64;

    // ---- layer 1: agg1 = segsum(xb); h = relu([agg1b|xb]@W1b^T + b1) --------
    {
        int total = N * (F_IN / 8);
        gather_agg_bf<F_IN, true><<<(total + 255) / 256, 256, 0, stream>>>(
            xb, off, deg, sbase, csr, (void*)agg1b, N, E, slice_size);
    }
    gemm_mfma<192, 128, true, true, true, false, true>
        <<<gemm_blocks, 256, 0, stream>>>(agg1b, xb, W1b, b1, nullptr, (void*)h, N);

    // ---- layer 2: t = h@W2rb^T; agg2 = segsum(t); out = h@W2sb^T + b2 + agg2
    gemm_mfma<128, 64, false, false, false, false, true>
        <<<gemm_blocks, 256, 0, stream>>>(h, nullptr, W2rb, nullptr, nullptr, (void*)t, N);
    {
        int total = N * (OUT_F / 8);
        gather_agg_bf<OUT_F, false><<<(total + 255) / 256, 256, 0, stream>>>(
            t, off, deg, sbase, csr, (void*)agg2, N, E, slice_size);
    }
    gemm_mfma<128, 64, false, false, true, true, false>
        <<<gemm_blocks, 256, 0, stream>>>(h, nullptr, W2sb, b2, agg2, (void*)out, N);
}

// Round 9
// 246.188 us; speedup vs baseline: 1.3729x; 1.0335x over previous
//
#include <hip/hip_runtime.h>

// GCN encoder, N=50000, E=800000.
// R9: (1) gather edge-loop unrolled 4x (4 independent L2 row loads in flight;
// loop is latency-bound, ~200cyc/L2 round trip); (2) deg_rank/place read ei
// as int4, place reads dst-first and loads src/rank only on slice match;
// (3) single setup kernel = convert x + weights + zero deg/counter (replaces
// 3 dispatches); (4) agg2 stored bf16 (halves gather2 write + gemm3 addend).
// MFMA bf16 GEMMs (LDS-free, fragment-direct loads) and sliced atomic-free
// CSR build carried from R8.

#define N_NODES 50000
#define F_IN    96
#define HIDDEN  128
#define OUT_F   64

typedef __attribute__((ext_vector_type(8))) short short8;
typedef __attribute__((ext_vector_type(4))) float floatx4;

__device__ inline unsigned short f2bf(float f) {          // RNE f32->bf16
    union { float f; unsigned u; } v; v.f = f;
    unsigned r = v.u + 0x7FFF + ((v.u >> 16) & 1);
    return (unsigned short)(r >> 16);
}
__device__ inline float bf2f(unsigned short b) {
    union { unsigned u; float f; } v; v.u = ((unsigned)b) << 16;
    return v.f;
}

// ---------------- setup: convert x + weights to bf16, zero deg/counter ------
__global__ __launch_bounds__(256) void setup_kernel(
    const float* __restrict__ x,
    const float* __restrict__ W1_rel, const float* __restrict__ W1_root,
    const float* __restrict__ W2_rel, const float* __restrict__ W2_root,
    unsigned short* __restrict__ xb, unsigned short* __restrict__ W1b,
    unsigned short* __restrict__ W2rb, unsigned short* __restrict__ W2sb,
    int* __restrict__ degz, int total8, int nzero)
{
    int i = blockIdx.x * 256 + threadIdx.x;
    if (i < total8) {
        const float4* p = (const float4*)(x + (size_t)i * 8);
        float4 v0 = p[0], v1 = p[1];
        short8 o;
        o[0] = (short)f2bf(v0.x); o[1] = (short)f2bf(v0.y);
        o[2] = (short)f2bf(v0.z); o[3] = (short)f2bf(v0.w);
        o[4] = (short)f2bf(v1.x); o[5] = (short)f2bf(v1.y);
        o[6] = (short)f2bf(v1.z); o[7] = (short)f2bf(v1.w);
        *(short8*)(xb + (size_t)i * 8) = o;
    }
    if (i < nzero) degz[i] = 0;
    if (i < 128 * 192) {
        int j = i / 192, k = i % 192;
        float v = (k < 96) ? W1_rel[j * 96 + k] : W1_root[j * 96 + k - 96];
        W1b[i] = f2bf(v);
    } else if (i < 128 * 192 + 64 * 128) {
        int i2 = i - 128 * 192;
        W2rb[i2] = f2bf(W2_rel[i2]);
    } else if (i < 128 * 192 + 2 * 64 * 128) {
        int i3 = i - 128 * 192 - 64 * 128;
        W2sb[i3] = f2bf(W2_root[i3]);
    }
}

// ---------------- CSR build ------------------------------------------------
// pass 1: degree + per-edge rank; int4 (4 edges/thread)
__global__ __launch_bounds__(256) void deg_rank_kernel(
    const int* __restrict__ ei, int* __restrict__ deg,
    int* __restrict__ rank, int E)
{
    int i4 = blockIdx.x * 256 + threadIdx.x;
    int E4 = E >> 2;
    if (i4 < E4) {
        int4 s4 = ((const int4*)ei)[i4];
        int4 d4 = ((const int4*)(ei + E))[i4];
        int e0 = i4 * 4;
        int ss[4] = {s4.x, s4.y, s4.z, s4.w};
        int dd[4] = {d4.x, d4.y, d4.z, d4.w};
        #pragma unroll
        for (int k = 0; k < 4; ++k) {
            int s = ss[k], d = dd[k];
            if (s != d && (unsigned)d < (unsigned)N_NODES)
                rank[e0 + k] = atomicAdd(&deg[d], 1);
        }
    } else if (i4 == E4) {
        for (int e = E4 * 4; e < E; ++e) {
            int s = ei[e], d = ei[E + e];
            if (s != d && (unsigned)d < (unsigned)N_NODES)
                rank[e] = atomicAdd(&deg[d], 1);
        }
    }
}

// per-slice, order-free segment allocation: off[n] = within-slice offset
__global__ __launch_bounds__(256) void alloc_kernel(
    const int* __restrict__ deg, int* __restrict__ off,
    int* __restrict__ counter, int N, int slice_size)
{
    int i = blockIdx.x * 256 + threadIdx.x;
    int lane = threadIdx.x & 63;
    int v = (i < N) ? deg[i] : 0;
    int s = v;
    #pragma unroll
    for (int d = 1; d < 64; d <<= 1) {
        int t = __shfl_up(s, d, 64);
        if (lane >= d) s += t;
    }
    int total = __shfl(s, 63, 64);
    int sl = (blockIdx.x * 256) / slice_size;
    int base = 0;
    if (lane == 63) base = atomicAdd(&counter[sl], total);
    base = __shfl(base, 63, 64);
    if (i < N) off[i] = base + s - v;
}

__global__ void scan8_kernel(const int* __restrict__ counter,
                             int* __restrict__ sbase)
{
    if (threadIdx.x == 0) {
        int run = 0;
        for (int s = 0; s < 8; ++s) { sbase[s] = run; run += counter[s]; }
    }
}

// pass 2: placement. blockIdx%8 -> slice (~XCD). dst read as int4; src/rank
// loaded only on slice match (~1/8 of lanes).
__global__ __launch_bounds__(256) void place_kernel(
    const int* __restrict__ ei, const int* __restrict__ off,
    const int* __restrict__ rank, const int* __restrict__ sbase,
    int* __restrict__ csr, int E, int slice_size)
{
    int sl = blockIdx.x & 7;
    int i4 = (blockIdx.x >> 3) * 256 + threadIdx.x;
    int sb = sbase[sl];
    int E4 = E >> 2;
    if (i4 < E4) {
        int4 d4 = ((const int4*)(ei + E))[i4];
        int e0 = i4 * 4;
        int dd[4] = {d4.x, d4.y, d4.z, d4.w};
        #pragma unroll
        for (int k = 0; k < 4; ++k) {
            int d = dd[k];
            if ((unsigned)d >= (unsigned)N_NODES) continue;
            if (d / slice_size != sl) continue;
            int e = e0 + k;
            int s = ei[e];
            if (s == d) continue;
            int p = sb + off[d] + rank[e];
            if ((unsigned)p < (unsigned)E)    // guard: invariant p < E
                csr[p] = s;
        }
    } else if (i4 == E4) {
        for (int e = E4 * 4; e < E; ++e) {
            int d = ei[E + e];
            if ((unsigned)d >= (unsigned)N_NODES) continue;
            if (d / slice_size != sl) continue;
            int s = ei[e];
            if (s == d) continue;
            int p = sb + off[d] + rank[e];
            if ((unsigned)p < (unsigned)E)
                csr[p] = s;
        }
    }
}

// ---------------- gather (bf16): agg[n] = sum feat[src], 4x unrolled ---------
template<int F>
__global__ __launch_bounds__(256) void gather_agg_bf(
    const unsigned short* __restrict__ feat, const int* __restrict__ off,
    const int* __restrict__ deg, const int* __restrict__ sbase,
    const int* __restrict__ csr, unsigned short* __restrict__ agg,
    int N, int E, int slice_size)
{
    constexpr int C = F / 8;
    int gid = blockIdx.x * 256 + threadIdx.x;
    int node = gid / C;
    int c = gid % C;
    if (node >= N) return;
    int j = sbase[node / slice_size] + off[node];
    int end = j + deg[node];
    if (j < 0) j = 0;                         // guards (no-ops when sane)
    if (end > E) end = E;
    float acc[8] = {};
    const unsigned short* fc = feat + c * 8;
    for (; j + 3 < end; j += 4) {             // 4 independent row loads
        int s0 = csr[j], s1 = csr[j + 1], s2 = csr[j + 2], s3 = csr[j + 3];
        short8 v0 = *(const short8*)(fc + (size_t)s0 * F);
        short8 v1 = *(const short8*)(fc + (size_t)s1 * F);
        short8 v2 = *(const short8*)(fc + (size_t)s2 * F);
        short8 v3 = *(const short8*)(fc + (size_t)s3 * F);
        #pragma unroll
        for (int i = 0; i < 8; ++i)
            acc[i] += (bf2f((unsigned short)v0[i]) + bf2f((unsigned short)v1[i]))
                    + (bf2f((unsigned short)v2[i]) + bf2f((unsigned short)v3[i]));
    }
    for (; j < end; ++j) {
        int s0 = csr[j];
        short8 v0 = *(const short8*)(fc + (size_t)s0 * F);
        #pragma unroll
        for (int i = 0; i < 8; ++i) acc[i] += bf2f((unsigned short)v0[i]);
    }
    short8 o;
    #pragma unroll
    for (int i = 0; i < 8; ++i) o[i] = (short)f2bf(acc[i]);
    *(short8*)(agg + (size_t)node * F + c * 8) = o;
}

// ---------------- MFMA GEMM: out = act(A@W^T + b [+ add]) --------------------
// A: [N,KT] bf16 row-major (SPLIT: halves in A1/A2), W: [NO,KT] bf16.
// LDS-free: 16B fragment loads straight from L2 in HW layout.
template<int KT, int NO, bool SPLIT, bool RELU, bool HAS_BIAS, bool HAS_ADD, bool OUT_BF>
__global__ __launch_bounds__(256) void gemm_mfma(
    const unsigned short* __restrict__ A1, const unsigned short* __restrict__ A2,
    const unsigned short* __restrict__ W, const float* __restrict__ bias,
    const unsigned short* __restrict__ addb, void* __restrict__ out, int N)
{
    constexpr int NC = KT / 32;
    const int lane = threadIdx.x & 63;
    const int wave = threadIdx.x >> 6;
    const int node_base = blockIdx.x * 64 + wave * 16;
    const int m = lane & 15, quad = lane >> 4;
    int na = node_base + m;
    if (na >= N) na = N - 1;                  // clamp: C rows >=N never stored
    short8 a[NC];
    #pragma unroll
    for (int c = 0; c < NC; ++c) {
        if (SPLIT) {
            constexpr int HK = KT / 2;
            if (c < NC / 2)
                a[c] = *(const short8*)(A1 + (size_t)na * HK + c * 32 + quad * 8);
            else
                a[c] = *(const short8*)(A2 + (size_t)na * HK + (c - NC / 2) * 32 + quad * 8);
        } else {
            a[c] = *(const short8*)(A1 + (size_t)na * KT + c * 32 + quad * 8);
        }
    }
    #pragma unroll
    for (int jt = 0; jt < NO / 16; ++jt) {
        floatx4 acc = {0.f, 0.f, 0.f, 0.f};
        const unsigned short* wb = W + (size_t)(jt * 16 + m) * KT + quad * 8;
        #pragma unroll
        for (int c = 0; c < NC; ++c) {
            short8 b = *(const short8*)(wb + c * 32);
            acc = __builtin_amdgcn_mfma_f32_16x16x32_bf16(a[c], b, acc, 0, 0, 0);
        }
        int col = jt * 16 + m;
        float bv = HAS_BIAS ? bias[col] : 0.f;
        #pragma unroll
        for (int r = 0; r < 4; ++r) {
            int node = node_base + quad * 4 + r;
            if (node < N) {
                float v = acc[r] + bv;
                if (HAS_ADD) v += bf2f(addb[(size_t)node * NO + col]);
                if (RELU) v = fmaxf(v, 0.f);
                if (OUT_BF) ((unsigned short*)out)[(size_t)node * NO + col] = f2bf(v);
                else        ((float*)out)[(size_t)node * NO + col] = v;
            }
        }
    }
}

extern "C" void kernel_launch(void* const* d_in, const int* in_sizes, int n_in,
                              void* d_out, int out_size, void* d_ws, size_t ws_size,
                              hipStream_t stream) {
    const float* x       = (const float*)d_in[0];
    const int*   ei      = (const int*)d_in[1];
    const float* W1_rel  = (const float*)d_in[2];
    const float* b1      = (const float*)d_in[3];
    const float* W1_root = (const float*)d_in[4];
    const float* W2_rel  = (const float*)d_in[5];
    const float* b2      = (const float*)d_in[6];
    const float* W2_root = (const float*)d_in[7];
    float* out = (float*)d_out;

    const int N = in_sizes[0] / F_IN;       // 50000
    const int E = in_sizes[1] / 2;          // 800000
    const int slice_size = ((N + 2047) / 2048) * 256;

    // Workspace (~52 MB):
    char* ws = (char*)d_ws;
    size_t p = 0;
    unsigned short* xb    = (unsigned short*)(ws + p); p += (size_t)N_NODES * F_IN * 2;   // 9.6M
    unsigned short* agg1b = (unsigned short*)(ws + p); p += (size_t)N_NODES * F_IN * 2;   // 9.6M
    unsigned short* h     = (unsigned short*)(ws + p); p += (size_t)N_NODES * HIDDEN * 2; // 12.8M
    unsigned short* t     = (unsigned short*)(ws + p); p += (size_t)N_NODES * OUT_F * 2;  // 6.4M
    unsigned short* agg2b = (unsigned short*)(ws + p); p += (size_t)N_NODES * OUT_F * 2;  // 6.4M
    unsigned short* W1b   = (unsigned short*)(ws + p); p += (size_t)128 * 192 * 2;
    unsigned short* W2rb  = (unsigned short*)(ws + p); p += (size_t)64 * 128 * 2;
    unsigned short* W2sb  = (unsigned short*)(ws + p); p += (size_t)64 * 128 * 2;
    int* deg     = (int*)(ws + p);  p += (size_t)N_NODES * 4;
    int* counter = (int*)(ws + p);  p += 8 * 4;         // contiguous with deg
    int* off     = (int*)(ws + p);  p += (size_t)N_NODES * 4;
    int* sbase   = (int*)(ws + p);  p += 8 * 4;
    int* rank    = (int*)(ws + p);  p += (size_t)800000 * 4;
    int* csr     = (int*)(ws + p);

    // ---- setup (convert + zero) and CSR build ----
    {
        int total8 = N * F_IN / 8;          // 600000 threads cover all tasks
        setup_kernel<<<(total8 + 255) / 256, 256, 0, stream>>>(
            x, W1_rel, W1_root, W2_rel, W2_root, xb, W1b, W2rb, W2sb,
            deg, total8, N + 8);
    }
    {
        int E4 = E >> 2;
        deg_rank_kernel<<<(E4 + 1 + 255) / 256, 256, 0, stream>>>(ei, deg, rank, E);
    }
    alloc_kernel<<<(N + 255) / 256, 256, 0, stream>>>(deg, off, counter, N, slice_size);
    scan8_kernel<<<1, 64, 0, stream>>>(counter, sbase);
    {
        int E4 = E >> 2;
        int bps = (E4 + 1 + 255) / 256;     // blocks per slice
        place_kernel<<<bps * 8, 256, 0, stream>>>(ei, off, rank, sbase, csr, E, slice_size);
    }

    const int gemm_blocks = (N + 63) / 64;

    // ---- layer 1: agg1 = segsum(xb); h = relu([agg1b|xb]@W1b^T + b1) --------
    {
        int total = N * (F_IN / 8);
        gather_agg_bf<F_IN><<<(total + 255) / 256, 256, 0, stream>>>(
            xb, off, deg, sbase, csr, agg1b, N, E, slice_size);
    }
    gemm_mfma<192, 128, true, true, true, false, true>
        <<<gemm_blocks, 256, 0, stream>>>(agg1b, xb, W1b, b1, nullptr, (void*)h, N);

    // ---- layer 2: t = h@W2rb^T; agg2 = segsum(t); out = h@W2sb^T + b2 + agg2
    gemm_mfma<128, 64, false, false, false, false, true>
        <<<gemm_blocks, 256, 0, stream>>>(h, nullptr, W2rb, nullptr, nullptr, (void*)t, N);
    {
        int total = N * (OUT_F / 8);
        gather_agg_bf<OUT_F><<<(total + 255) / 256, 256, 0, stream>>>(
            t, off, deg, sbase, csr, agg2b, N, E, slice_size);
    }
    gemm_mfma<128, 64, false, false, true, true, false>
        <<<gemm_blocks, 256, 0, stream>>>(h, nullptr, W2sb, b2, agg2b, (void*)out, N);
}